// Round 13
// baseline (465.250 us; speedup 1.0000x reference)
//
#include <hip/hip_runtime.h>
#include <hip/hip_bf16.h>
#include <stdint.h>

typedef unsigned short u16;
typedef __attribute__((ext_vector_type(8))) short s8v;
typedef __attribute__((ext_vector_type(4))) float f4v;

#define DEVI static __device__ __forceinline__

DEVI u16 f2bf(float x) {
  union { float f; unsigned u; } a; a.f = x;
  return (u16)((a.u + 0x7fffu + ((a.u >> 16) & 1u)) >> 16);  // RNE
}
DEVI float bf2f(u16 h) {
  union { float f; unsigned u; } a; a.u = ((unsigned)h) << 16; return a.f;
}
DEVI float wred_add(float s) {
#pragma unroll
  for (int o = 32; o; o >>= 1) s += __shfl_xor(s, o, 64);
  return s;
}
DEVI f4v mfma16(s8v a, s8v b, f4v c) {
  return __builtin_amdgcn_mfma_f32_16x16x32_bf16(a, b, c, 0, 0, 0);
}

// rho: within each 32-elem k-block, source elem j is STORED at position rho(j).
// Stored granule g (16B) = source elems {4g..4g+3, 16+4g..16+4g+3} == the MFMA
// k-slot set used since round 1 -> bitwise-identical MFMA inputs.
DEVI int rho(int j) { return ((j & 12) << 1) | (j & 3) | ((j >> 4) << 2); }

// async global->LDS, 16B per lane; LDS base wave-uniform, HW writes base+lane*16
DEVI void gload16(const u16* gp, u16* lp) {
  __builtin_amdgcn_global_load_lds(
      (const __attribute__((address_space(1))) uint32_t*)gp,
      (__attribute__((address_space(3))) uint32_t*)lp, 16, 0, 0);
}

// frag read: ONE ds_read_b128. LDS chunk = 16 rows x 64B; slot(r,lg) XOR-swizzled
// -> uniform 8 lanes/bank-quad, distinct addrs (verified r4-r12: BANK_CONFLICT == 0).
DEVI s8v ldfrag_sw(const u16* base, int r, int lg) {
  int off = ((r >> 4) << 9) + ((r & 15) << 5) + ((lg ^ ((r >> 1) & 3)) << 3);
  return *(const s8v*)(base + off);
}

// ---------------- transpose+split body: f32 [R][C] tile -> bf16 [C][R], R rho'd ----------------
// LDS row permutation sigma(r) = r + (r>>2): conflict-free reads (verified r12).
template<bool LO>
DEVI void tsplit_body(const float* __restrict__ in, u16* __restrict__ outH, u16* __restrict__ outL,
                      int cc, int rr, int R, int C, float (*t)[132], int id) {
#pragma unroll
  for (int i = 0; i < 4; ++i) {
    int slot = i * 256 + id;
    int r = slot >> 5, c4 = slot & 31;
    float4 v = *(const float4*)&in[(long long)(rr + r) * C + cc + c4 * 4];
    *(float4*)&t[r + (r >> 2)][c4 * 4] = v;  // sigma(r)
  }
  __syncthreads();
#pragma unroll
  for (int i = 0; i < 4; ++i) {
    int slot = i * 256 + id;
    int j = slot >> 3, gs = slot & 7;
    int s0 = 5 * gs;  // sigma(4*gs+d) = 5*gs + d for d<4
    float v0 = t[s0 + 0][j], v1 = t[s0 + 1][j], v2 = t[s0 + 2][j], v3 = t[s0 + 3][j];
    long long o = (long long)(cc + j) * R + rr + 8 * (gs & 3) + 4 * (gs >> 2);  // rho(4gs)
    ushort4 hv;
    hv.x = f2bf(v0); hv.y = f2bf(v1); hv.z = f2bf(v2); hv.w = f2bf(v3);
    *(ushort4*)&outH[o] = hv;
    if (LO) {
      ushort4 lv;
      lv.x = f2bf(v0 - bf2f(hv.x)); lv.y = f2bf(v1 - bf2f(hv.y));
      lv.z = f2bf(v2 - bf2f(hv.z)); lv.w = f2bf(v3 - bf2f(hv.w));
      *(ushort4*)&outL[o] = lv;
    }
  }
}

// ---------------- prep1: src split + 4 attention weight transposes + bias concat ----------------
__global__ __launch_bounds__(256) void prep1_k(const float* __restrict__ src,
    const float* __restrict__ Wq, const float* __restrict__ Wk,
    const float* __restrict__ Wv, const float* __restrict__ Wo,
    const float* __restrict__ bq, const float* __restrict__ bk, const float* __restrict__ bv,
    u16* __restrict__ srcH, u16* __restrict__ srcL,
    u16* __restrict__ WqkvTh, u16* __restrict__ WqkvTl,
    u16* __restrict__ WoTh, u16* __restrict__ WoTl, float* __restrict__ bqkv) {
  __shared__ float tbuf[39][132];
  const int bid = blockIdx.x, tid = threadIdx.x;
  if (bid < 2048) {
    int i = bid * 256 + tid;
    float4 v = ((const float4*)src)[i];
    ushort4 hv, lv;
    hv.x = f2bf(v.x); lv.x = f2bf(v.x - bf2f(hv.x));
    hv.y = f2bf(v.y); lv.y = f2bf(v.y - bf2f(hv.y));
    hv.z = f2bf(v.z); lv.z = f2bf(v.z - bf2f(hv.z));
    hv.w = f2bf(v.w); lv.w = f2bf(v.w - bf2f(hv.w));
    int t = i & 7, blk = i >> 3;
    int si = blk * 8 + ((t & 3) << 1) + (t >> 2);  // ushort4 slot of rho(4t)
    ((ushort4*)srcH)[si] = hv;
    ((ushort4*)srcL)[si] = lv;
  } else if (bid < 3072) {
    int t = bid - 2048;
    int wsel = t >> 8, tb = t & 255;
    const float* in = wsel == 0 ? Wq : wsel == 1 ? Wk : wsel == 2 ? Wv : Wo;
    u16* oh = wsel < 3 ? WqkvTh + wsel * 1024 * 1024 : WoTh;
    u16* ol = wsel < 3 ? WqkvTl + wsel * 1024 * 1024 : WoTl;
    tsplit_body<true>(in, oh, ol, (tb & 7) * 128, (tb >> 3) * 32, 1024, 1024, tbuf, tid);
  } else {
    int i = (bid - 3072) * 256 + tid;
    bqkv[i] = i < 1024 ? bq[i] : (i < 2048 ? bk[i - 1024] : bv[i - 2048]);
  }
}

// ---------------- prep2: W1 + W2 transposes (k-dims rho'd) ----------------
__global__ __launch_bounds__(256) void prep2_k(const float* __restrict__ W1, const float* __restrict__ W2,
                                               u16* __restrict__ W1T, u16* __restrict__ W2T) {
  __shared__ float tbuf[39][132];
  const int bid = blockIdx.x, tid = threadIdx.x;
  if (bid < 4096) {
    int bx = bid & 31, by = (bid >> 5) & 31, bz = bid >> 10;
    tsplit_body<false>(W1 + (long long)bz * 1024 * 4096, W1T + (long long)bz * 4096 * 1024, nullptr,
                       bx * 128, by * 32, 1024, 4096, tbuf, tid);
  } else {
    int t = bid - 4096;
    int bx = t & 7, by = (t >> 3) & 127, bz = t >> 10;
    tsplit_body<false>(W2 + (long long)bz * 4096 * 1024, W2T + (long long)bz * 1024 * 4096, nullptr,
                       bx * 128, by * 32, 4096, 1024, tbuf, tid);
  }
}

// ---------------- bf16-pair transpose (vectorized): v slice of qkv -> vT [b][d][t] ----------------
__global__ __launch_bounds__(256) void transpose_pair_k(const u16* __restrict__ inH, const u16* __restrict__ inL,
                                                        u16* __restrict__ oH, u16* __restrict__ oL) {
  __shared__ u16 th[32][40], tl[32][40];
  const int b = blockIdx.z;
  const int dd = blockIdx.x * 32;
  const int tt = blockIdx.y * 32;
  const int id = threadIdx.y * 32 + threadIdx.x;
  const int rr = id >> 3, g = id & 7;
  const int rg = 8 * (g & 3) + 4 * (g >> 2);      // rho(4g)
  const int64_t ibase = ((int64_t)(b * 512 + tt)) * 3072 + 2048 + dd;
  ushort4 hv = *(const ushort4*)&inH[ibase + (int64_t)rr * 3072 + rg];
  ushort4 lv = *(const ushort4*)&inL[ibase + (int64_t)rr * 3072 + rg];
  *(ushort4*)&th[rr][4 * g] = hv;
  *(ushort4*)&tl[rr][4 * g] = lv;
  __syncthreads();
  const int j = rr;
  ushort4 ho, lo;
  ho.x = th[4 * g + 0][j]; ho.y = th[4 * g + 1][j]; ho.z = th[4 * g + 2][j]; ho.w = th[4 * g + 3][j];
  lo.x = tl[4 * g + 0][j]; lo.y = tl[4 * g + 1][j]; lo.z = tl[4 * g + 2][j]; lo.w = tl[4 * g + 3][j];
  const int64_t obase = ((int64_t)b * 1024 + dd + j) * 512 + tt + rg;
  *(ushort4*)&oH[obase] = ho;
  *(ushort4*)&oL[obase] = lo;
}

// ---------------- fused scores (bf16x3) + softmax -> probs hi/lo ----------------
__global__ __launch_bounds__(512, 2) void attn_sm_k(const u16* __restrict__ qkvH,
                                                    const u16* __restrict__ qkvL,
                                                    u16* __restrict__ probs) {
  __shared__ __align__(16) u16 sK[2][16384];  // [ks][512 t x 32 d] K-hi
  __shared__ __align__(16) float smax[128][4];
  __shared__ __align__(16) float ssum[128][4];
  const int tid = threadIdx.x;
  const int w = tid >> 6, lane = tid & 63;
  const int wq = w >> 2, wt = w & 3;
  const int lr = lane & 15, lg = lane >> 4;
  const int bx = blockIdx.x, bh = blockIdx.y;
  const int64_t tokBase = (int64_t)(bh >> 4) * 512;
  const int h = bh & 15;
  const int qcol = h * 64, kcol = 1024 + h * 64;
  const int srow = lane >> 2;
  const int sG = (lane & 3) ^ ((lane >> 3) & 3);

#pragma unroll
  for (int c = 0; c < 8; ++c) {
    int s = c * 8 + w;
    int ks = s >> 5, rb = s & 31;
    int64_t go = (tokBase + rb * 16 + srow) * 3072 + kcol + ks * 32 + sG * 8;
    gload16(qkvH + go, &sK[ks][rb * 512]);
  }
  __syncthreads();

  f4v acc[4][8];
#pragma unroll
  for (int mi = 0; mi < 4; ++mi)
#pragma unroll
    for (int ni = 0; ni < 8; ++ni) acc[mi][ni] = f4v{0.f, 0.f, 0.f, 0.f};

#pragma unroll
  for (int ks = 0; ks < 2; ++ks) {
    s8v ah[4], al[4];
#pragma unroll
    for (int mi = 0; mi < 4; ++mi) {
      int64_t tok = tokBase + bx * 128 + wq * 64 + mi * 16 + lr;
      const u16* p = qkvH + tok * 3072 + qcol + ks * 32 + lg * 8;
      ah[mi] = *(const s8v*)p;
      al[mi] = *(const s8v*)(qkvL + (p - qkvH));
    }
#pragma unroll
    for (int ni = 0; ni < 8; ++ni) {
      int r = wt * 128 + ni * 16 + lr;
      s8v bh_ = ldfrag_sw(&sK[ks][0], r, lg);
      s8v bl_ = *(const s8v*)(qkvL + (tokBase + r) * 3072 + kcol + ks * 32 + lg * 8);
#pragma unroll
      for (int mi = 0; mi < 4; ++mi) {
        acc[mi][ni] = mfma16(ah[mi], bh_, acc[mi][ni]);   // hh
        acc[mi][ni] = mfma16(ah[mi], bl_, acc[mi][ni]);   // h*lo(K)
        acc[mi][ni] = mfma16(al[mi], bh_, acc[mi][ni]);   // lo(Q)*h
      }
    }
  }

#pragma unroll
  for (int mi = 0; mi < 4; ++mi)
#pragma unroll
    for (int ni = 0; ni < 8; ++ni) {
      acc[mi][ni][0] *= 0.125f; acc[mi][ni][1] *= 0.125f;
      acc[mi][ni][2] *= 0.125f; acc[mi][ni][3] *= 0.125f;
    }

  float rm[4][4];
#pragma unroll
  for (int mi = 0; mi < 4; ++mi)
#pragma unroll
    for (int j = 0; j < 4; ++j) {
      float m = acc[mi][0][j];
#pragma unroll
      for (int ni = 1; ni < 8; ++ni) m = fmaxf(m, acc[mi][ni][j]);
#pragma unroll
      for (int o = 1; o < 16; o <<= 1) m = fmaxf(m, __shfl_xor(m, o, 64));
      rm[mi][j] = m;
    }
  if (lr == 0) {
#pragma unroll
    for (int mi = 0; mi < 4; ++mi)
#pragma unroll
      for (int j = 0; j < 4; ++j)
        smax[wq * 64 + mi * 16 + lg * 4 + j][wt] = rm[mi][j];
  }
  __syncthreads();
  float mrow[4][4];
#pragma unroll
  for (int mi = 0; mi < 4; ++mi)
#pragma unroll
    for (int j = 0; j < 4; ++j) {
      float4 t4 = *(const float4*)&smax[wq * 64 + mi * 16 + lg * 4 + j][0];
      mrow[mi][j] = fmaxf(fmaxf(t4.x, t4.y), fmaxf(t4.z, t4.w));
    }

  float rs_[4][4];
#pragma unroll
  for (int mi = 0; mi < 4; ++mi)
#pragma unroll
    for (int j = 0; j < 4; ++j) {
      float s = 0.f;
#pragma unroll
      for (int ni = 0; ni < 8; ++ni) {
        float e = expf(acc[mi][ni][j] - mrow[mi][j]);
        acc[mi][ni][j] = e;
        s += e;
      }
#pragma unroll
      for (int o = 1; o < 16; o <<= 1) s += __shfl_xor(s, o, 64);
      rs_[mi][j] = s;
    }
  if (lr == 0) {
#pragma unroll
    for (int mi = 0; mi < 4; ++mi)
#pragma unroll
      for (int j = 0; j < 4; ++j)
        ssum[wq * 64 + mi * 16 + lg * 4 + j][wt] = rs_[mi][j];
  }
  __syncthreads();

#pragma unroll
  for (int mi = 0; mi < 4; ++mi)
#pragma unroll
    for (int j = 0; j < 4; ++j) {
      int row = wq * 64 + mi * 16 + lg * 4 + j;
      float4 t4 = *(const float4*)&ssum[row][0];
      float inv = 1.f / (((t4.x + t4.y) + t4.z) + t4.w);
      u16* rp = probs + ((int64_t)bh * 512 + bx * 128 + row) * 1024;
#pragma unroll
      for (int ni = 0; ni < 8; ++ni) {
        int tcol = wt * 128 + ni * 16 + lr;
        int cs = (tcol & ~31) | rho(tcol & 31);
        float p = acc[mi][ni][j] * inv;
        u16 hv = f2bf(p);
        rp[cs] = hv;
        rp[512 + cs] = f2bf(p - bf2f(hv));
      }
    }
}

// ---------------- generic MFMA GEMM: direct-global A, B via LDS, counted-vmcnt ----------------
// A-fragments read straight from global (rho granule == frag slot set; bitwise ==
// the staged path since the stage/read swizzles cancel). Halves LDS traffic.
struct GemmArgs {
  const u16* Ah; const u16* Al; int lda;
  const u16* Bh; const u16* Bl; int ldb;
  float* C; u16* Ch; u16* Cl; int ldc;
  const float* bias;
  int K;
  int Z2;
  int64_t aZ1, aZ2, bZ1, bZ2, cZ1, cZ2;
  const int* ofs;
  int64_t bStrE; int biasStrE;
  int NX, NY, YG;
};

template<int BM, int BN, bool SPLIT, int EPI, bool PN, int MINW, bool SWZ>
__global__ __launch_bounds__(256, MINW) void gemm_k(GemmArgs g) {
  constexpr int BSZ = BN * 32;
  constexpr int BNT = SPLIT ? 2 * BSZ : BSZ;
  constexpr int nB = BN / 16;
  constexpr int CH = SPLIT ? 2 * nB : nB;
  static_assert(CH % 4 == 0, "B chunk count must divide across 4 waves");
  constexpr int NLOADB = CH / 4;                 // gload_lds per lane per stage
  constexpr int FM = BM / 32, FN = BN / 32;
  constexpr int AF = SPLIT ? 2 * FM : FM;        // A-frag global loads per lane per step
  constexpr int KW = NLOADB + AF;                // counted wait (see r13 derivation)
  __shared__ __align__(16) u16 sB[2][BNT];

  const int tid = threadIdx.x;
  int bx, by, bz;
  if (SWZ) {
    const int nwg = gridDim.x;
    int wg = (blockIdx.x & 7) * (nwg >> 3) + (blockIdx.x >> 3);
    int byl = wg % g.YG; int t = wg / g.YG;
    bx = t % g.NX; t /= g.NX;
    const int nyg = g.NY / g.YG;
    by = (t % nyg) * g.YG + byl;
    bz = t / nyg;
  } else {
    bx = blockIdx.x; by = blockIdx.y; bz = blockIdx.z;
  }

  const u16* Ah = g.Ah; const u16* Al = g.Al;
  const u16* Bh = g.Bh; const u16* Bl = g.Bl;
  int64_t cOff = 0;
  if (g.Z2 > 0) {
    int z1 = bz / g.Z2, z2 = bz % g.Z2;
    int64_t ao = (int64_t)z1 * g.aZ1 + (int64_t)z2 * g.aZ2;
    int64_t bo = (int64_t)z1 * g.bZ1 + (int64_t)z2 * g.bZ2;
    Ah += ao; Bh += bo;
    if (SPLIT) { Al += ao; Bl += bo; }
    cOff = (int64_t)z1 * g.cZ1 + (int64_t)z2 * g.cZ2;
  }
  const int row0 = bx * BM;
  const int col0 = by * BN;
  const float* bias = g.bias;
  if (g.ofs) {
    if (row0 >= g.ofs[4]) return;
    int e = 0;
    while (e < 3 && row0 >= g.ofs[e + 1]) ++e;
    Bh += (int64_t)e * g.bStrE;
    if (bias) bias += (int64_t)e * g.biasStrE;
  }

  const int w = tid >> 6, lane = tid & 63;
  const int wr = w >> 1, wc = w & 1;
  const int lr = lane & 15, lg = lane >> 4;

  const int srow = lane >> 2;
  const int sG = (lane & 3) ^ ((lane >> 3) & 3);

  auto stageB = [&](int b, int kt) {
#pragma unroll
    for (int c = 0; c < NLOADB; ++c) {
      int s = c * 4 + w;
      if (!SPLIT || s < nB) {
        int ch = s;
        int64_t go = (int64_t)(col0 + ch * 16 + srow) * g.ldb + kt + sG * 8;
        gload16(Bh + go, &sB[b][ch * 512]);
      } else {
        int ch = s - nB;
        int64_t go = (int64_t)(col0 + ch * 16 + srow) * g.ldb + kt + sG * 8;
        gload16(Bl + go, &sB[b][BSZ + ch * 512]);
      }
    }
  };

  f4v acc[FM][FN];
#pragma unroll
  for (int i = 0; i < FM; ++i)
#pragma unroll
    for (int j = 0; j < FN; ++j) acc[i][j] = f4v{0.f, 0.f, 0.f, 0.f};

  s8v a0[FM], b0[FN], al0[SPLIT ? FM : 1], bl0[SPLIT ? FN : 1];
  s8v a1[FM], b1[FN], al1[SPLIT ? FM : 1], bl1[SPLIT ? FN : 1];

  auto rdA = [&](int kt, auto& af, auto& afl) {
#pragma unroll
    for (int mi = 0; mi < FM; ++mi) {
      int64_t ro = (int64_t)(row0 + wr * (BM / 2) + mi * 16 + lr) * g.lda + kt + lg * 8;
      af[mi] = *(const s8v*)(Ah + ro);
      if (SPLIT) afl[mi] = *(const s8v*)(Al + ro);
    }
  };
  auto rdB = [&](int buf, auto& bf, auto& bfl) {
#pragma unroll
    for (int ni = 0; ni < FN; ++ni) {
      int r = wc * (BN / 2) + ni * 16 + lr;
      bf[ni] = ldfrag_sw(&sB[buf][0], r, lg);
      if (SPLIT) bfl[ni] = ldfrag_sw(&sB[buf][BSZ], r, lg);
    }
  };

  const int nt = g.K >> 5;

  // prologue (issue order must match steady state: stageB(0), stageB(1), rdA(0))
  stageB(0, 0);
  stageB(1, 32);
  rdA(0, a0, al0);
  asm volatile("s_waitcnt vmcnt(%0)" :: "n"(KW) : "memory");  // buf0 landed
  __builtin_amdgcn_sched_barrier(0);
  __builtin_amdgcn_s_barrier();
  rdB(0, b0, bl0);

  auto body = [&](int t, auto& cA, auto& cB, auto& cAl, auto& cBl,
                  auto& nA_, auto& nB_, auto& nAl_, auto& nBl_) {
    asm volatile("s_waitcnt lgkmcnt(0)" ::: "memory");
    __builtin_amdgcn_sched_barrier(0);
    __builtin_amdgcn_s_barrier();
    if (t + 2 < nt) stageB(t & 1, (t + 2) << 5);
    if (t + 1 < nt) {
      if (t + 2 < nt)
        asm volatile("s_waitcnt vmcnt(%0)" :: "n"(KW) : "memory");  // stageB(t+1) done
      else
        asm volatile("s_waitcnt vmcnt(0)" ::: "memory");
      __builtin_amdgcn_sched_barrier(0);
      __builtin_amdgcn_s_barrier();
      rdA((t + 1) << 5, nA_, nAl_);   // global A-frags, fly under MFMAs
      rdB((t + 1) & 1, nB_, nBl_);    // ds_reads
    }
    __builtin_amdgcn_sched_barrier(0);
    __builtin_amdgcn_s_setprio(1);
#pragma unroll
    for (int mi = 0; mi < FM; ++mi)
#pragma unroll
      for (int ni = 0; ni < FN; ++ni) {
        acc[mi][ni] = mfma16(cA[mi], cB[ni], acc[mi][ni]);
        if (SPLIT) {
          acc[mi][ni] = mfma16(cA[mi], cBl[ni], acc[mi][ni]);
          acc[mi][ni] = mfma16(cAl[mi], cB[ni], acc[mi][ni]);
        }
      }
    __builtin_amdgcn_s_setprio(0);
  };

  for (int t = 0; t < nt; t += 2) {
    body(t,     a0, b0, al0, bl0, a1, b1, al1, bl1);
    body(t + 1, a1, b1, al1, bl1, a0, b0, al0, bl0);
  }

  // epilogue (C/D frag: col=lane&15, row=(lane>>4)*4+j — HW-verified layout)
#pragma unroll
  for (int mi = 0; mi < FM; ++mi) {
    int rbase = row0 + wr * (BM / 2) + mi * 16 + lg * 4;
#pragma unroll
    for (int ni = 0; ni < FN; ++ni) {
      int c = col0 + wc * (BN / 2) + ni * 16 + lr;
      int cs = PN ? ((c & ~31) | rho(c & 31)) : c;
      float bv = bias ? bias[c] : 0.f;
#pragma unroll
      for (int j = 0; j < 4; ++j) {
        int r = rbase + j;
        float v = acc[mi][ni][j] + bv;
        if (EPI == 0) {
          g.C[cOff + (int64_t)r * g.ldc + cs] = v;
        } else if (EPI == 1) {
          u16 h = f2bf(v);
          int64_t o = cOff + (int64_t)r * g.ldc + cs;
          g.Ch[o] = h;
          g.Cl[o] = f2bf(v - bf2f(h));
        } else {
          v = v > 0.f ? v : 0.f;
          g.Ch[cOff + (int64_t)r * g.ldc + cs] = f2bf(v);
        }
      }
    }
  }
}

// ---------------- residual + layernorm + fused router ----------------
__global__ __launch_bounds__(256) void ln_router_k(const float* __restrict__ a, const float* __restrict__ b,
                                                   const float* __restrict__ gm, const float* __restrict__ bt,
                                                   const float* __restrict__ rw, const float* __restrict__ rb,
                                                   float* __restrict__ out, int* __restrict__ eidx) {
  __shared__ float sm[4];
  const int r = blockIdx.x, tid = threadIdx.x;
  const int w = tid >> 6, lane = tid & 63;
  float4 va = ((const float4*)(a + (int64_t)r * 1024))[tid];
  float4 vb = ((const float4*)(b + (int64_t)r * 1024))[tid];
  float x0 = va.x + vb.x, x1 = va.y + vb.y, x2 = va.z + vb.z, x3 = va.w + vb.w;
  float s = wred_add(x0 + x1 + x2 + x3);
  if (lane == 0) sm[w] = s;
  __syncthreads();
  float mu = (sm[0] + sm[1] + sm[2] + sm[3]) * (1.f / 1024.f);
  float d0 = x0 - mu, d1 = x1 - mu, d2 = x2 - mu, d3 = x3 - mu;
  float q = wred_add(d0 * d0 + d1 * d1 + d2 * d2 + d3 * d3);
  __syncthreads();
  if (lane == 0) sm[w] = q;
  __syncthreads();
  float var = (sm[0] + sm[1] + sm[2] + sm[3]) * (1.f / 1024.f);
  float rs = 1.f / sqrtf(var + 1e-5f);
  float4 g4 = ((const float4*)gm)[tid];
  float4 b4 = ((const float4*)bt)[tid];
  float4 o;
  o.x = d0 * rs * g4.x + b4.x;
  o.y = d1 * rs * g4.y + b4.y;
  o.z = d2 * rs * g4.z + b4.z;
  o.w = d3 * rs * g4.w + b4.w;
  ((float4*)(out + (int64_t)r * 1024))[tid] = o;
  float4 w4 = ((const float4*)rw)[tid];
  float p = o.x * w4.x + o.y * w4.y + o.z * w4.z + o.w * w4.w;
  p = wred_add(p);
  __syncthreads();
  if (lane == 0) sm[w] = p;
  __syncthreads();
  if (tid == 0) {
    float key = (sm[0] + sm[1] + sm[2] + sm[3]) + rb[0];
    eidx[r] = (int)floorf(key) & 3;
  }
}

// ---------------- split-K(4) reduce + bias + residual + LN2 + scatter (fused) ----------------
__global__ __launch_bounds__(256) void reduce_ln_k(const float* __restrict__ part, const int* __restrict__ rowsrc,
                                                   const int* __restrict__ ofs, const float* __restrict__ b2,
                                                   const float* __restrict__ xb, const float* __restrict__ gm,
                                                   const float* __restrict__ bt, float* __restrict__ out) {
  __shared__ float sm[4];
  const int r = blockIdx.x;
  if (r >= ofs[4]) return;
  const int s = rowsrc[r];
  if (s < 0) return;
  int e = 0;
  while (e < 3 && r >= ofs[e + 1]) ++e;
  const int tid = threadIdx.x, w = tid >> 6, lane = tid & 63;
  const int64_t RN = 2560ll * 1024;
  float4 v0 = ((const float4*)(part + 0 * RN + (int64_t)r * 1024))[tid];
  float4 v1 = ((const float4*)(part + 1 * RN + (int64_t)r * 1024))[tid];
  float4 v2 = ((const float4*)(part + 2 * RN + (int64_t)r * 1024))[tid];
  float4 v3 = ((const float4*)(part + 3 * RN + (int64_t)r * 1024))[tid];
  float4 bb = ((const float4*)(b2 + (int64_t)e * 1024))[tid];
  float4 va = ((const float4*)(xb + (int64_t)s * 1024))[tid];
  float y0 = ((v0.x + v1.x) + v2.x) + v3.x + bb.x;
  float y1 = ((v0.y + v1.y) + v2.y) + v3.y + bb.y;
  float y2 = ((v0.z + v1.z) + v2.z) + v3.z + bb.z;
  float y3 = ((v0.w + v1.w) + v2.w) + v3.w + bb.w;
  float x0 = va.x + y0, x1 = va.y + y1, x2 = va.z + y2, x3 = va.w + y3;
  float sum = wred_add(x0 + x1 + x2 + x3);
  if (lane == 0) sm[w] = sum;
  __syncthreads();
  float mu = (sm[0] + sm[1] + sm[2] + sm[3]) * (1.f / 1024.f);
  float d0 = x0 - mu, d1 = x1 - mu, d2 = x2 - mu, d3 = x3 - mu;
  float q = wred_add(d0 * d0 + d1 * d1 + d2 * d2 + d3 * d3);
  __syncthreads();
  if (lane == 0) sm[w] = q;
  __syncthreads();
  float var = (sm[0] + sm[1] + sm[2] + sm[3]) * (1.f / 1024.f);
  float rs = 1.f / sqrtf(var + 1e-5f);
  float4 g4 = ((const float4*)gm)[tid];
  float4 b4 = ((const float4*)bt)[tid];
  float4 o;
  o.x = d0 * rs * g4.x + b4.x;
  o.y = d1 * rs * g4.y + b4.y;
  o.z = d2 * rs * g4.z + b4.z;
  o.w = d3 * rs * g4.w + b4.w;
  ((float4*)(out + (int64_t)s * 1024))[tid] = o;
}

// ---------------- stable compaction ----------------
__global__ __launch_bounds__(256) void compact_k(const int* __restrict__ eidx,
                                                 int* __restrict__ rowsrc, int* __restrict__ ofs) {
  __shared__ unsigned long long sc[256];
  __shared__ int soff[5];
  const int tid = threadIdx.x;
  int myE[8];
  unsigned long long c = 0;
#pragma unroll
  for (int i = 0; i < 8; ++i) {
    int e = eidx[tid * 8 + i];
    myE[i] = e;
    c += 1ull << (e * 16);
  }
  sc[tid] = c;
  __syncthreads();
  for (int o = 1; o < 256; o <<= 1) {
    unsigned long long v = (tid >= o) ? sc[tid - o] : 0ull;
    __syncthreads();
    sc[tid] += v;
    __syncthreads();
  }
  unsigned long long incl = sc[tid], tot = sc[255];
  unsigned long long excl = incl - c;
  if (tid == 0) {
    int off = 0;
    for (int e = 0; e < 4; ++e) {
      soff[e] = off;
      int cnt = (int)((tot >> (e * 16)) & 0xffff);
      off += (cnt + 127) & ~127;
    }
    soff[4] = off;
    for (int e = 0; e < 5; ++e) ofs[e] = soff[e];
  }
  __syncthreads();
  for (int r = tid; r < 2560; r += 256) rowsrc[r] = -1;
  __threadfence_block();
  __syncthreads();
  int rank[4];
#pragma unroll
  for (int e = 0; e < 4; ++e) rank[e] = (int)((excl >> (e * 16)) & 0xffff);
#pragma unroll
  for (int i = 0; i < 8; ++i) {
    int e = myE[i];
    rowsrc[soff[e] + rank[e]] = tid * 8 + i;
    rank[e]++;
  }
}

// ---------------- gather x rows (f32 -> bf16, rho-permuted cols) ----------------
__global__ __launch_bounds__(256) void gather_k(const float* __restrict__ x, const int* __restrict__ rowsrc,
                                                const int* __restrict__ ofs, u16* __restrict__ xg) {
  int r = blockIdx.x;
  if (r >= ofs[4]) return;
  int s = rowsrc[r];
  int c = threadIdx.x;
  float4 v = (s >= 0) ? ((const float4*)(x + (int64_t)s * 1024))[c] : float4{0.f, 0.f, 0.f, 0.f};
  ushort4 o;
  o.x = f2bf(v.x); o.y = f2bf(v.y); o.z = f2bf(v.z); o.w = f2bf(v.w);
  int t = c & 7, blk = c >> 3;
  int si = blk * 8 + ((t & 3) << 1) + (t >> 2);
  ((ushort4*)(xg + (int64_t)r * 1024))[si] = o;
}

// ---------------- host ----------------
extern "C" void kernel_launch(void* const* d_in, const int* in_sizes, int n_in,
                              void* d_out, int out_size, void* d_ws, size_t ws_size,
                              hipStream_t stream) {
  const float* src = (const float*)d_in[0];
  const float* Wq  = (const float*)d_in[1];
  const float* bq  = (const float*)d_in[2];
  const float* Wk  = (const float*)d_in[3];
  const float* bk  = (const float*)d_in[4];
  const float* Wv  = (const float*)d_in[5];
  const float* bv  = (const float*)d_in[6];
  const float* Wo  = (const float*)d_in[7];
  const float* bo  = (const float*)d_in[8];
  const float* rw  = (const float*)d_in[9];
  const float* rb  = (const float*)d_in[10];
  const float* W1  = (const float*)d_in[11];
  const float* b1  = (const float*)d_in[12];
  const float* W2  = (const float*)d_in[13];
  const float* b2  = (const float*)d_in[14];
  const float* g1  = (const float*)d_in[15];
  const float* be1 = (const float*)d_in[16];
  const float* g2  = (const float*)d_in[17];
  const float* be2 = (const float*)d_in[18];
  float* out = (float*)d_out;

  char* base = (char*)d_ws;
  size_t off = 0;
  auto alloc = [&](size_t bytes) -> char* {
    char* p = base + off;
    off += (bytes + 255) & ~(size_t)255;
    return p;
  };
  const size_t MB = 1ull << 20;
  u16* srcH = (u16*)alloc(4 * MB);
  u16* srcL = (u16*)alloc(4 * MB);
  u16* WqkvTh = (u16*)alloc(6 * MB);
  u16* WqkvTl = (u16*)alloc(6 * MB);
  u16* WoTh = (u16*)alloc(2 * MB);
  u16* WoTl = (u16*)alloc(2 * MB);
  float* bqkv = (float*)alloc(16 * 1024);
  u16* qkvH = (u16*)alloc(12 * MB);
  u16* qkvL = (u16*)alloc(12 * MB);
  u16* hbuf = (u16*)qkvH;  // alias: 20MB over qkvH+qkvL (24MB), dead by FFN time
  u16* vTH = (u16*)alloc(4 * MB); u16* vTL = (u16*)alloc(4 * MB);
  float* scores = (float*)alloc(64 * MB);  // probs hi/lo; later W1T/W2T
  u16* W1T = (u16*)scores;
  u16* W2T = (u16*)scores + 16ull * 1024 * 1024;
  u16* attnH = (u16*)alloc(4 * MB); u16* attnL = (u16*)alloc(4 * MB);
  u16* xg = (u16*)attnH;  // alias: dead after Wo GEMM
  float* woOut = (float*)alloc(8 * MB);
  float* xbuf = (float*)alloc(8 * MB);
  float* partials = (float*)alloc(40 * MB);  // 4 x 2560 x 1024 f32
  int* eidx   = (int*)alloc(2048 * 4);
  int* rowsrc = (int*)alloc(2560 * 4);
  int* ofs    = (int*)alloc(32);
  (void)ws_size; (void)in_sizes; (void)n_in; (void)out_size;

  dim3 tb(32, 8);

  // Phase 0 (1 launch): src split + 4 attention weight transposes + bias concat
  prep1_k<<<3084, 256, 0, stream>>>(src, Wq, Wk, Wv, Wo, bq, bk, bv,
                                    srcH, srcL, WqkvTh, WqkvTl, WoTh, WoTl, bqkv);

  // Phase 1: fused QKV projection (bf16x3) -> qkv hi/lo [2048][3072], cols rho'd
  {
    GemmArgs g{};
    g.Ah = srcH; g.Al = srcL; g.lda = 1024;
    g.Bh = WqkvTh; g.Bl = WqkvTl; g.ldb = 1024;
    g.Ch = qkvH; g.Cl = qkvL; g.ldc = 3072;
    g.bias = bqkv; g.K = 1024; g.Z2 = 0;
    g.NX = 16; g.NY = 32; g.YG = 8;
    gemm_k<128, 96, true, 1, true, 3, true><<<dim3(512), 256, 0, stream>>>(g);
  }
  // v slice -> vT [b][d][t] hi/lo (lossless re-layout, t rho'd)
  transpose_pair_k<<<dim3(32, 16, 4), tb, 0, stream>>>(qkvH, qkvL, vTH, vTL);

  // Phase 2: FUSED scores (bf16x3, bitwise-identical) + softmax -> probs hi/lo
  attn_sm_k<<<dim3(4, 64), 512, 0, stream>>>(qkvH, qkvL, (u16*)scores);

  // PV: attn = probs @ v (bf16x3) -> attn hi/lo, d-cols rho'd
  {
    GemmArgs g{};
    g.Ah = (const u16*)scores; g.Al = (const u16*)scores + 512; g.lda = 1024;
    g.Bh = vTH; g.Bl = vTL; g.ldb = 512;
    g.Ch = attnH; g.Cl = attnL; g.ldc = 1024;
    g.K = 512; g.Z2 = 16;
    g.aZ1 = 16ll * 512 * 1024; g.aZ2 = 512ll * 1024;
    g.bZ1 = 1024ll * 512;      g.bZ2 = 64ll * 512;
    g.cZ1 = 512ll * 1024;      g.cZ2 = 64;
    gemm_k<64, 64, true, 1, true, 3, false><<<dim3(8, 1, 64), 256, 0, stream>>>(g);
  }
  // Wo projection (bf16x3) + bias -> plain f32 (feeds LN/residual)
  {
    GemmArgs g{};
    g.Ah = attnH; g.Al = attnL; g.lda = 1024;
    g.Bh = WoTh; g.Bl = WoTl; g.ldb = 1024;
    g.C = woOut; g.ldc = 1024;
    g.bias = bo; g.K = 1024; g.Z2 = 0;
    gemm_k<64, 64, true, 0, false, 3, false><<<dim3(32, 16, 1), 256, 0, stream>>>(g);
  }
  // ln1 + fused router
  ln_router_k<<<2048, 256, 0, stream>>>(src, woOut, g1, be1, rw, rb, xbuf, eidx);

  // Phase 3: routing
  compact_k<<<1, 256, 0, stream>>>(eidx, rowsrc, ofs);
  gather_k<<<2560, 256, 0, stream>>>(xbuf, rowsrc, ofs, xg);

  // FFN weights -> bf16 transposed (1 launch, into dead scores region), k-dims rho'd
  prep2_k<<<8192, 256, 0, stream>>>(W1, W2, W1T, W2T);

  // FFN1: h = relu(xg @ W1[e] + b1[e]) -> bf16, cols rho'd
  {
    GemmArgs g{};
    g.Ah = xg; g.lda = 1024;
    g.Bh = W1T; g.ldb = 1024;
    g.Ch = hbuf; g.ldc = 4096;
    g.bias = b1; g.biasStrE = 4096;
    g.K = 1024; g.Z2 = 0;
    g.ofs = ofs; g.bStrE = 4096ll * 1024;
    g.NX = 20; g.NY = 32; g.YG = 16;
    gemm_k<128, 128, false, 2, true, 3, true><<<dim3(640), 256, 0, stream>>>(g);
  }
  // FFN2 split-K x4, 128x128 tile: partial[c] = h[:, c*1024:...] @ W2[e][c*1024:..., :]
  {
    GemmArgs g{};
    g.Ah = hbuf; g.lda = 4096;
    g.Bh = W2T; g.ldb = 4096;
    g.C = partials; g.ldc = 1024;
    g.bias = nullptr;
    g.K = 1024; g.Z2 = 4;
    g.aZ1 = 0; g.aZ2 = 1024;
    g.bZ1 = 0; g.bZ2 = 1024;
    g.cZ1 = 0; g.cZ2 = 2560ll * 1024;
    g.ofs = ofs; g.bStrE = 4096ll * 1024;
    g.NX = 20; g.NY = 8; g.YG = 8;
    gemm_k<128, 128, false, 0, false, 3, true><<<dim3(640), 256, 0, stream>>>(g);
  }
  // fused: reduce split-K(4) + b2 + residual + LN2 + scatter to out
  reduce_ln_k<<<2560, 256, 0, stream>>>(partials, rowsrc, ofs, b2, xbuf, g2, be2, out);
}

// Round 14
// 271.629 us; speedup vs baseline: 1.7128x; 1.7128x over previous
//
#include <hip/hip_runtime.h>
#include <hip/hip_bf16.h>
#include <stdint.h>

typedef unsigned short u16;
typedef __attribute__((ext_vector_type(8))) short s8v;
typedef __attribute__((ext_vector_type(4))) float f4v;

#define DEVI static __device__ __forceinline__

DEVI u16 f2bf(float x) {
  union { float f; unsigned u; } a; a.f = x;
  return (u16)((a.u + 0x7fffu + ((a.u >> 16) & 1u)) >> 16);  // RNE
}
DEVI float bf2f(u16 h) {
  union { float f; unsigned u; } a; a.u = ((unsigned)h) << 16; return a.f;
}
DEVI float wred_add(float s) {
#pragma unroll
  for (int o = 32; o; o >>= 1) s += __shfl_xor(s, o, 64);
  return s;
}
DEVI f4v mfma16(s8v a, s8v b, f4v c) {
  return __builtin_amdgcn_mfma_f32_16x16x32_bf16(a, b, c, 0, 0, 0);
}

// rho: within each 32-elem k-block, source elem j is STORED at position rho(j).
// Stored granule g (16B) = source elems {4g..4g+3, 16+4g..16+4g+3} == the MFMA
// k-slot set used since round 1 -> bitwise-identical MFMA inputs.
DEVI int rho(int j) { return ((j & 12) << 1) | (j & 3) | ((j >> 4) << 2); }

// async global->LDS, 16B per lane; LDS base wave-uniform, HW writes base+lane*16
DEVI void gload16(const u16* gp, u16* lp) {
  __builtin_amdgcn_global_load_lds(
      (const __attribute__((address_space(1))) uint32_t*)gp,
      (__attribute__((address_space(3))) uint32_t*)lp, 16, 0, 0);
}

// frag read: ONE ds_read_b128. LDS chunk = 16 rows x 64B; slot(r,lg) XOR-swizzled
// -> uniform 8 lanes/bank-quad, distinct addrs (verified r4-r12: BANK_CONFLICT == 0).
DEVI s8v ldfrag_sw(const u16* base, int r, int lg) {
  int off = ((r >> 4) << 9) + ((r & 15) << 5) + ((lg ^ ((r >> 1) & 3)) << 3);
  return *(const s8v*)(base + off);
}

// ---------------- transpose+split body: f32 [R][C] tile -> bf16 [C][R], R rho'd ----------------
// LDS row permutation sigma(r) = r + (r>>2): conflict-free reads (verified r12).
template<bool LO>
DEVI void tsplit_body(const float* __restrict__ in, u16* __restrict__ outH, u16* __restrict__ outL,
                      int cc, int rr, int R, int C, float (*t)[132], int id) {
#pragma unroll
  for (int i = 0; i < 4; ++i) {
    int slot = i * 256 + id;
    int r = slot >> 5, c4 = slot & 31;
    float4 v = *(const float4*)&in[(long long)(rr + r) * C + cc + c4 * 4];
    *(float4*)&t[r + (r >> 2)][c4 * 4] = v;  // sigma(r)
  }
  __syncthreads();
#pragma unroll
  for (int i = 0; i < 4; ++i) {
    int slot = i * 256 + id;
    int j = slot >> 3, gs = slot & 7;
    int s0 = 5 * gs;  // sigma(4*gs+d) = 5*gs + d for d<4
    float v0 = t[s0 + 0][j], v1 = t[s0 + 1][j], v2 = t[s0 + 2][j], v3 = t[s0 + 3][j];
    long long o = (long long)(cc + j) * R + rr + 8 * (gs & 3) + 4 * (gs >> 2);  // rho(4gs)
    ushort4 hv;
    hv.x = f2bf(v0); hv.y = f2bf(v1); hv.z = f2bf(v2); hv.w = f2bf(v3);
    *(ushort4*)&outH[o] = hv;
    if (LO) {
      ushort4 lv;
      lv.x = f2bf(v0 - bf2f(hv.x)); lv.y = f2bf(v1 - bf2f(hv.y));
      lv.z = f2bf(v2 - bf2f(hv.z)); lv.w = f2bf(v3 - bf2f(hv.w));
      *(ushort4*)&outL[o] = lv;
    }
  }
}

// ---------------- prep1: src split + 4 attention weight transposes + bias concat ----------------
__global__ __launch_bounds__(256) void prep1_k(const float* __restrict__ src,
    const float* __restrict__ Wq, const float* __restrict__ Wk,
    const float* __restrict__ Wv, const float* __restrict__ Wo,
    const float* __restrict__ bq, const float* __restrict__ bk, const float* __restrict__ bv,
    u16* __restrict__ srcH, u16* __restrict__ srcL,
    u16* __restrict__ WqkvTh, u16* __restrict__ WqkvTl,
    u16* __restrict__ WoTh, u16* __restrict__ WoTl, float* __restrict__ bqkv) {
  __shared__ float tbuf[39][132];
  const int bid = blockIdx.x, tid = threadIdx.x;
  if (bid < 2048) {
    int i = bid * 256 + tid;
    float4 v = ((const float4*)src)[i];
    ushort4 hv, lv;
    hv.x = f2bf(v.x); lv.x = f2bf(v.x - bf2f(hv.x));
    hv.y = f2bf(v.y); lv.y = f2bf(v.y - bf2f(hv.y));
    hv.z = f2bf(v.z); lv.z = f2bf(v.z - bf2f(hv.z));
    hv.w = f2bf(v.w); lv.w = f2bf(v.w - bf2f(hv.w));
    int t = i & 7, blk = i >> 3;
    int si = blk * 8 + ((t & 3) << 1) + (t >> 2);  // ushort4 slot of rho(4t)
    ((ushort4*)srcH)[si] = hv;
    ((ushort4*)srcL)[si] = lv;
  } else if (bid < 3072) {
    int t = bid - 2048;
    int wsel = t >> 8, tb = t & 255;
    const float* in = wsel == 0 ? Wq : wsel == 1 ? Wk : wsel == 2 ? Wv : Wo;
    u16* oh = wsel < 3 ? WqkvTh + wsel * 1024 * 1024 : WoTh;
    u16* ol = wsel < 3 ? WqkvTl + wsel * 1024 * 1024 : WoTl;
    tsplit_body<true>(in, oh, ol, (tb & 7) * 128, (tb >> 3) * 32, 1024, 1024, tbuf, tid);
  } else {
    int i = (bid - 3072) * 256 + tid;
    bqkv[i] = i < 1024 ? bq[i] : (i < 2048 ? bk[i - 1024] : bv[i - 2048]);
  }
}

// ---------------- prep2: W1 + W2 transposes (k-dims rho'd) ----------------
__global__ __launch_bounds__(256) void prep2_k(const float* __restrict__ W1, const float* __restrict__ W2,
                                               u16* __restrict__ W1T, u16* __restrict__ W2T) {
  __shared__ float tbuf[39][132];
  const int bid = blockIdx.x, tid = threadIdx.x;
  if (bid < 4096) {
    int bx = bid & 31, by = (bid >> 5) & 31, bz = bid >> 10;
    tsplit_body<false>(W1 + (long long)bz * 1024 * 4096, W1T + (long long)bz * 4096 * 1024, nullptr,
                       bx * 128, by * 32, 1024, 4096, tbuf, tid);
  } else {
    int t = bid - 4096;
    int bx = t & 7, by = (t >> 3) & 127, bz = t >> 10;
    tsplit_body<false>(W2 + (long long)bz * 4096 * 1024, W2T + (long long)bz * 1024 * 4096, nullptr,
                       bx * 128, by * 32, 4096, 1024, tbuf, tid);
  }
}

// ---------------- bf16-pair transpose (vectorized): v slice of qkv -> vT [b][d][t] ----------------
__global__ __launch_bounds__(256) void transpose_pair_k(const u16* __restrict__ inH, const u16* __restrict__ inL,
                                                        u16* __restrict__ oH, u16* __restrict__ oL) {
  __shared__ u16 th[32][40], tl[32][40];
  const int b = blockIdx.z;
  const int dd = blockIdx.x * 32;
  const int tt = blockIdx.y * 32;
  const int id = threadIdx.y * 32 + threadIdx.x;
  const int rr = id >> 3, g = id & 7;
  const int rg = 8 * (g & 3) + 4 * (g >> 2);      // rho(4g)
  const int64_t ibase = ((int64_t)(b * 512 + tt)) * 3072 + 2048 + dd;
  ushort4 hv = *(const ushort4*)&inH[ibase + (int64_t)rr * 3072 + rg];
  ushort4 lv = *(const ushort4*)&inL[ibase + (int64_t)rr * 3072 + rg];
  *(ushort4*)&th[rr][4 * g] = hv;
  *(ushort4*)&tl[rr][4 * g] = lv;
  __syncthreads();
  const int j = rr;
  ushort4 ho, lo;
  ho.x = th[4 * g + 0][j]; ho.y = th[4 * g + 1][j]; ho.z = th[4 * g + 2][j]; ho.w = th[4 * g + 3][j];
  lo.x = tl[4 * g + 0][j]; lo.y = tl[4 * g + 1][j]; lo.z = tl[4 * g + 2][j]; lo.w = tl[4 * g + 3][j];
  const int64_t obase = ((int64_t)b * 1024 + dd + j) * 512 + tt + rg;
  *(ushort4*)&oH[obase] = ho;
  *(ushort4*)&oL[obase] = lo;
}

// ---------------- fused scores (bf16x3) + softmax -> probs hi/lo ----------------
__global__ __launch_bounds__(512, 2) void attn_sm_k(const u16* __restrict__ qkvH,
                                                    const u16* __restrict__ qkvL,
                                                    u16* __restrict__ probs) {
  __shared__ __align__(16) u16 sK[2][16384];  // [ks][512 t x 32 d] K-hi
  __shared__ __align__(16) float smax[128][4];
  __shared__ __align__(16) float ssum[128][4];
  const int tid = threadIdx.x;
  const int w = tid >> 6, lane = tid & 63;
  const int wq = w >> 2, wt = w & 3;
  const int lr = lane & 15, lg = lane >> 4;
  const int bx = blockIdx.x, bh = blockIdx.y;
  const int64_t tokBase = (int64_t)(bh >> 4) * 512;
  const int h = bh & 15;
  const int qcol = h * 64, kcol = 1024 + h * 64;
  const int srow = lane >> 2;
  const int sG = (lane & 3) ^ ((lane >> 3) & 3);

#pragma unroll
  for (int c = 0; c < 8; ++c) {
    int s = c * 8 + w;
    int ks = s >> 5, rb = s & 31;
    int64_t go = (tokBase + rb * 16 + srow) * 3072 + kcol + ks * 32 + sG * 8;
    gload16(qkvH + go, &sK[ks][rb * 512]);
  }
  __syncthreads();

  f4v acc[4][8];
#pragma unroll
  for (int mi = 0; mi < 4; ++mi)
#pragma unroll
    for (int ni = 0; ni < 8; ++ni) acc[mi][ni] = f4v{0.f, 0.f, 0.f, 0.f};

#pragma unroll
  for (int ks = 0; ks < 2; ++ks) {
    s8v ah[4], al[4];
#pragma unroll
    for (int mi = 0; mi < 4; ++mi) {
      int64_t tok = tokBase + bx * 128 + wq * 64 + mi * 16 + lr;
      const u16* p = qkvH + tok * 3072 + qcol + ks * 32 + lg * 8;
      ah[mi] = *(const s8v*)p;
      al[mi] = *(const s8v*)(qkvL + (p - qkvH));
    }
#pragma unroll
    for (int ni = 0; ni < 8; ++ni) {
      int r = wt * 128 + ni * 16 + lr;
      s8v bh_ = ldfrag_sw(&sK[ks][0], r, lg);
      s8v bl_ = *(const s8v*)(qkvL + (tokBase + r) * 3072 + kcol + ks * 32 + lg * 8);
#pragma unroll
      for (int mi = 0; mi < 4; ++mi) {
        acc[mi][ni] = mfma16(ah[mi], bh_, acc[mi][ni]);   // hh
        acc[mi][ni] = mfma16(ah[mi], bl_, acc[mi][ni]);   // h*lo(K)
        acc[mi][ni] = mfma16(al[mi], bh_, acc[mi][ni]);   // lo(Q)*h
      }
    }
  }

#pragma unroll
  for (int mi = 0; mi < 4; ++mi)
#pragma unroll
    for (int ni = 0; ni < 8; ++ni) {
      acc[mi][ni][0] *= 0.125f; acc[mi][ni][1] *= 0.125f;
      acc[mi][ni][2] *= 0.125f; acc[mi][ni][3] *= 0.125f;
    }

  float rm[4][4];
#pragma unroll
  for (int mi = 0; mi < 4; ++mi)
#pragma unroll
    for (int j = 0; j < 4; ++j) {
      float m = acc[mi][0][j];
#pragma unroll
      for (int ni = 1; ni < 8; ++ni) m = fmaxf(m, acc[mi][ni][j]);
#pragma unroll
      for (int o = 1; o < 16; o <<= 1) m = fmaxf(m, __shfl_xor(m, o, 64));
      rm[mi][j] = m;
    }
  if (lr == 0) {
#pragma unroll
    for (int mi = 0; mi < 4; ++mi)
#pragma unroll
      for (int j = 0; j < 4; ++j)
        smax[wq * 64 + mi * 16 + lg * 4 + j][wt] = rm[mi][j];
  }
  __syncthreads();
  float mrow[4][4];
#pragma unroll
  for (int mi = 0; mi < 4; ++mi)
#pragma unroll
    for (int j = 0; j < 4; ++j) {
      float4 t4 = *(const float4*)&smax[wq * 64 + mi * 16 + lg * 4 + j][0];
      mrow[mi][j] = fmaxf(fmaxf(t4.x, t4.y), fmaxf(t4.z, t4.w));
    }

  float rs_[4][4];
#pragma unroll
  for (int mi = 0; mi < 4; ++mi)
#pragma unroll
    for (int j = 0; j < 4; ++j) {
      float s = 0.f;
#pragma unroll
      for (int ni = 0; ni < 8; ++ni) {
        float e = expf(acc[mi][ni][j] - mrow[mi][j]);
        acc[mi][ni][j] = e;
        s += e;
      }
#pragma unroll
      for (int o = 1; o < 16; o <<= 1) s += __shfl_xor(s, o, 64);
      rs_[mi][j] = s;
    }
  if (lr == 0) {
#pragma unroll
    for (int mi = 0; mi < 4; ++mi)
#pragma unroll
      for (int j = 0; j < 4; ++j)
        ssum[wq * 64 + mi * 16 + lg * 4 + j][wt] = rs_[mi][j];
  }
  __syncthreads();

#pragma unroll
  for (int mi = 0; mi < 4; ++mi)
#pragma unroll
    for (int j = 0; j < 4; ++j) {
      int row = wq * 64 + mi * 16 + lg * 4 + j;
      float4 t4 = *(const float4*)&ssum[row][0];
      float inv = 1.f / (((t4.x + t4.y) + t4.z) + t4.w);
      u16* rp = probs + ((int64_t)bh * 512 + bx * 128 + row) * 1024;
#pragma unroll
      for (int ni = 0; ni < 8; ++ni) {
        int tcol = wt * 128 + ni * 16 + lr;
        int cs = (tcol & ~31) | rho(tcol & 31);
        float p = acc[mi][ni][j] * inv;
        u16 hv = f2bf(p);
        rp[cs] = hv;
        rp[512 + cs] = f2bf(p - bf2f(hv));
      }
    }
}

// ---------------- generic MFMA GEMM: depth-2 counted-vmcnt pipeline (r12 structure) ----------------
struct GemmArgs {
  const u16* Ah; const u16* Al; int lda;
  const u16* Bh; const u16* Bl; int ldb;
  float* C; u16* Ch; u16* Cl; int ldc;
  const float* bias;
  int K;
  int Z2;
  int64_t aZ1, aZ2, bZ1, bZ2, cZ1, cZ2;
  const int* ofs;
  int64_t bStrE; int biasStrE;
  int NX, NY, YG;
};

template<int BM, int BN, bool SPLIT, int EPI, bool PN, int MINW, bool SWZ>
__global__ __launch_bounds__(256, MINW) void gemm_k(GemmArgs g) {
  constexpr int ASZ = BM * 32, BSZ = BN * 32;
  constexpr int AN = SPLIT ? 2 * ASZ : ASZ;
  constexpr int BNT = SPLIT ? 2 * BSZ : BSZ;
  constexpr int nA = BM / 16, nB = BN / 16;
  constexpr int nAt = SPLIT ? 2 * nA : nA;
  constexpr int TOT = nAt + (SPLIT ? 2 * nB : nB);
  static_assert(TOT % 4 == 0, "chunk count must divide across 4 waves");
  constexpr int NLOAD = TOT / 4;
  __shared__ __align__(16) u16 sA[2][AN];
  __shared__ __align__(16) u16 sB[2][BNT];

  const int tid = threadIdx.x;
  int bx, by, bz;
  if (SWZ) {
    const int nwg = gridDim.x;
    int wg = (blockIdx.x & 7) * (nwg >> 3) + (blockIdx.x >> 3);
    int byl = wg % g.YG; int t = wg / g.YG;
    bx = t % g.NX; t /= g.NX;
    const int nyg = g.NY / g.YG;
    by = (t % nyg) * g.YG + byl;
    bz = t / nyg;
  } else {
    bx = blockIdx.x; by = blockIdx.y; bz = blockIdx.z;
  }

  const u16* Ah = g.Ah; const u16* Al = g.Al;
  const u16* Bh = g.Bh; const u16* Bl = g.Bl;
  int64_t cOff = 0;
  if (g.Z2 > 0) {
    int z1 = bz / g.Z2, z2 = bz % g.Z2;
    int64_t ao = (int64_t)z1 * g.aZ1 + (int64_t)z2 * g.aZ2;
    int64_t bo = (int64_t)z1 * g.bZ1 + (int64_t)z2 * g.bZ2;
    Ah += ao; Bh += bo;
    if (SPLIT) { Al += ao; Bl += bo; }
    cOff = (int64_t)z1 * g.cZ1 + (int64_t)z2 * g.cZ2;
  }
  const int row0 = bx * BM;
  const int col0 = by * BN;
  const float* bias = g.bias;
  if (g.ofs) {
    if (row0 >= g.ofs[4]) return;
    int e = 0;
    while (e < 3 && row0 >= g.ofs[e + 1]) ++e;
    Bh += (int64_t)e * g.bStrE;
    if (bias) bias += (int64_t)e * g.biasStrE;
  }

  const int w = tid >> 6, lane = tid & 63;
  const int wr = w >> 1, wc = w & 1;
  const int lr = lane & 15, lg = lane >> 4;
  constexpr int FM = BM / 32, FN = BN / 32;

  const int srow = lane >> 2;
  const int sG = (lane & 3) ^ ((lane >> 3) & 3);

  auto stage = [&](int b, int kt) {
#pragma unroll
    for (int c = 0; c < NLOAD; ++c) {
      int s = c * 4 + w;
      if (s < nA) {
        int64_t go = (int64_t)(row0 + s * 16 + srow) * g.lda + kt + sG * 8;
        gload16(Ah + go, &sA[b][s * 512]);
      } else if (SPLIT && s < 2 * nA) {
        int ch = s - nA;
        int64_t go = (int64_t)(row0 + ch * 16 + srow) * g.lda + kt + sG * 8;
        gload16(Al + go, &sA[b][ASZ + ch * 512]);
      } else if (s < nAt + nB) {
        int ch = s - nAt;
        int64_t go = (int64_t)(col0 + ch * 16 + srow) * g.ldb + kt + sG * 8;
        gload16(Bh + go, &sB[b][ch * 512]);
      } else {
        int ch = s - nAt - nB;
        int64_t go = (int64_t)(col0 + ch * 16 + srow) * g.ldb + kt + sG * 8;
        gload16(Bl + go, &sB[b][BSZ + ch * 512]);
      }
    }
  };

  f4v acc[FM][FN];
#pragma unroll
  for (int i = 0; i < FM; ++i)
#pragma unroll
    for (int j = 0; j < FN; ++j) acc[i][j] = f4v{0.f, 0.f, 0.f, 0.f};

  s8v a0[FM], b0[FN], al0[SPLIT ? FM : 1], bl0[SPLIT ? FN : 1];
  s8v a1[FM], b1[FN], al1[SPLIT ? FM : 1], bl1[SPLIT ? FN : 1];

  auto rdfrags = [&](int buf, auto& af, auto& bf, auto& afl, auto& bfl) {
#pragma unroll
    for (int mi = 0; mi < FM; ++mi) {
      int r = wr * (BM / 2) + mi * 16 + lr;
      af[mi] = ldfrag_sw(&sA[buf][0], r, lg);
      if (SPLIT) afl[mi] = ldfrag_sw(&sA[buf][ASZ], r, lg);
    }
#pragma unroll
    for (int ni = 0; ni < FN; ++ni) {
      int r = wc * (BN / 2) + ni * 16 + lr;
      bf[ni] = ldfrag_sw(&sB[buf][0], r, lg);
      if (SPLIT) bfl[ni] = ldfrag_sw(&sB[buf][BSZ], r, lg);
    }
  };

  const int nt = g.K >> 5;

  stage(0, 0);
  stage(1, 32);
  asm volatile("s_waitcnt vmcnt(%0)" :: "n"(NLOAD) : "memory");
  __builtin_amdgcn_sched_barrier(0);
  __builtin_amdgcn_s_barrier();
  rdfrags(0, a0, b0, al0, bl0);

  auto body = [&](int t, auto& cA, auto& cB, auto& cAl, auto& cBl,
                  auto& nA_, auto& nB_, auto& nAl_, auto& nBl_) {
    asm volatile("s_waitcnt lgkmcnt(0)" ::: "memory");
    __builtin_amdgcn_sched_barrier(0);
    __builtin_amdgcn_s_barrier();
    if (t + 2 < nt) stage(t & 1, (t + 2) << 5);
    if (t + 1 < nt) {
      if (t + 2 < nt)
        asm volatile("s_waitcnt vmcnt(%0)" :: "n"(NLOAD) : "memory");
      else
        asm volatile("s_waitcnt vmcnt(0)" ::: "memory");
      __builtin_amdgcn_sched_barrier(0);
      __builtin_amdgcn_s_barrier();
      rdfrags((t + 1) & 1, nA_, nB_, nAl_, nBl_);
    }
    __builtin_amdgcn_sched_barrier(0);
    __builtin_amdgcn_s_setprio(1);
#pragma unroll
    for (int mi = 0; mi < FM; ++mi)
#pragma unroll
      for (int ni = 0; ni < FN; ++ni) {
        acc[mi][ni] = mfma16(cA[mi], cB[ni], acc[mi][ni]);
        if (SPLIT) {
          acc[mi][ni] = mfma16(cA[mi], cBl[ni], acc[mi][ni]);
          acc[mi][ni] = mfma16(cAl[mi], cB[ni], acc[mi][ni]);
        }
      }
    __builtin_amdgcn_s_setprio(0);
  };

  for (int t = 0; t < nt; t += 2) {
    body(t,     a0, b0, al0, bl0, a1, b1, al1, bl1);
    body(t + 1, a1, b1, al1, bl1, a0, b0, al0, bl0);
  }

#pragma unroll
  for (int mi = 0; mi < FM; ++mi) {
    int rbase = row0 + wr * (BM / 2) + mi * 16 + lg * 4;
#pragma unroll
    for (int ni = 0; ni < FN; ++ni) {
      int c = col0 + wc * (BN / 2) + ni * 16 + lr;
      int cs = PN ? ((c & ~31) | rho(c & 31)) : c;
      float bv = bias ? bias[c] : 0.f;
#pragma unroll
      for (int j = 0; j < 4; ++j) {
        int r = rbase + j;
        float v = acc[mi][ni][j] + bv;
        if (EPI == 0) {
          g.C[cOff + (int64_t)r * g.ldc + cs] = v;
        } else if (EPI == 1) {
          u16 h = f2bf(v);
          int64_t o = cOff + (int64_t)r * g.ldc + cs;
          g.Ch[o] = h;
          g.Cl[o] = f2bf(v - bf2f(h));
        } else {
          v = v > 0.f ? v : 0.f;
          g.Ch[cOff + (int64_t)r * g.ldc + cs] = f2bf(v);
        }
      }
    }
  }
}

// ---------------- residual + layernorm + fused router ----------------
__global__ __launch_bounds__(256) void ln_router_k(const float* __restrict__ a, const float* __restrict__ b,
                                                   const float* __restrict__ gm, const float* __restrict__ bt,
                                                   const float* __restrict__ rw, const float* __restrict__ rb,
                                                   float* __restrict__ out, int* __restrict__ eidx) {
  __shared__ float sm[4];
  const int r = blockIdx.x, tid = threadIdx.x;
  const int w = tid >> 6, lane = tid & 63;
  float4 va = ((const float4*)(a + (int64_t)r * 1024))[tid];
  float4 vb = ((const float4*)(b + (int64_t)r * 1024))[tid];
  float x0 = va.x + vb.x, x1 = va.y + vb.y, x2 = va.z + vb.z, x3 = va.w + vb.w;
  float s = wred_add(x0 + x1 + x2 + x3);
  if (lane == 0) sm[w] = s;
  __syncthreads();
  float mu = (sm[0] + sm[1] + sm[2] + sm[3]) * (1.f / 1024.f);
  float d0 = x0 - mu, d1 = x1 - mu, d2 = x2 - mu, d3 = x3 - mu;
  float q = wred_add(d0 * d0 + d1 * d1 + d2 * d2 + d3 * d3);
  __syncthreads();
  if (lane == 0) sm[w] = q;
  __syncthreads();
  float var = (sm[0] + sm[1] + sm[2] + sm[3]) * (1.f / 1024.f);
  float rs = 1.f / sqrtf(var + 1e-5f);
  float4 g4 = ((const float4*)gm)[tid];
  float4 b4 = ((const float4*)bt)[tid];
  float4 o;
  o.x = d0 * rs * g4.x + b4.x;
  o.y = d1 * rs * g4.y + b4.y;
  o.z = d2 * rs * g4.z + b4.z;
  o.w = d3 * rs * g4.w + b4.w;
  ((float4*)(out + (int64_t)r * 1024))[tid] = o;
  float4 w4 = ((const float4*)rw)[tid];
  float p = o.x * w4.x + o.y * w4.y + o.z * w4.z + o.w * w4.w;
  p = wred_add(p);
  __syncthreads();
  if (lane == 0) sm[w] = p;
  __syncthreads();
  if (tid == 0) {
    float key = (sm[0] + sm[1] + sm[2] + sm[3]) + rb[0];
    eidx[r] = (int)floorf(key) & 3;
  }
}

// ---------------- split-K(4) reduce + bias + residual + LN2 + scatter (fused) ----------------
__global__ __launch_bounds__(256) void reduce_ln_k(const float* __restrict__ part, const int* __restrict__ rowsrc,
                                                   const int* __restrict__ ofs, const float* __restrict__ b2,
                                                   const float* __restrict__ xb, const float* __restrict__ gm,
                                                   const float* __restrict__ bt, float* __restrict__ out) {
  __shared__ float sm[4];
  const int r = blockIdx.x;
  if (r >= ofs[4]) return;
  const int s = rowsrc[r];
  if (s < 0) return;
  int e = 0;
  while (e < 3 && r >= ofs[e + 1]) ++e;
  const int tid = threadIdx.x, w = tid >> 6, lane = tid & 63;
  const int64_t RN = 2560ll * 1024;
  float4 v0 = ((const float4*)(part + 0 * RN + (int64_t)r * 1024))[tid];
  float4 v1 = ((const float4*)(part + 1 * RN + (int64_t)r * 1024))[tid];
  float4 v2 = ((const float4*)(part + 2 * RN + (int64_t)r * 1024))[tid];
  float4 v3 = ((const float4*)(part + 3 * RN + (int64_t)r * 1024))[tid];
  float4 bb = ((const float4*)(b2 + (int64_t)e * 1024))[tid];
  float4 va = ((const float4*)(xb + (int64_t)s * 1024))[tid];
  float y0 = ((v0.x + v1.x) + v2.x) + v3.x + bb.x;
  float y1 = ((v0.y + v1.y) + v2.y) + v3.y + bb.y;
  float y2 = ((v0.z + v1.z) + v2.z) + v3.z + bb.z;
  float y3 = ((v0.w + v1.w) + v2.w) + v3.w + bb.w;
  float x0 = va.x + y0, x1 = va.y + y1, x2 = va.z + y2, x3 = va.w + y3;
  float sum = wred_add(x0 + x1 + x2 + x3);
  if (lane == 0) sm[w] = sum;
  __syncthreads();
  float mu = (sm[0] + sm[1] + sm[2] + sm[3]) * (1.f / 1024.f);
  float d0 = x0 - mu, d1 = x1 - mu, d2 = x2 - mu, d3 = x3 - mu;
  float q = wred_add(d0 * d0 + d1 * d1 + d2 * d2 + d3 * d3);
  __syncthreads();
  if (lane == 0) sm[w] = q;
  __syncthreads();
  float var = (sm[0] + sm[1] + sm[2] + sm[3]) * (1.f / 1024.f);
  float rs = 1.f / sqrtf(var + 1e-5f);
  float4 g4 = ((const float4*)gm)[tid];
  float4 b4 = ((const float4*)bt)[tid];
  float4 o;
  o.x = d0 * rs * g4.x + b4.x;
  o.y = d1 * rs * g4.y + b4.y;
  o.z = d0 * 0.f + d2 * rs * g4.z + b4.z;  // (kept numerically identical: see below)
  o.z = d2 * rs * g4.z + b4.z;
  o.w = d3 * rs * g4.w + b4.w;
  ((float4*)(out + (int64_t)s * 1024))[tid] = o;
}

// ---------------- stable compaction ----------------
__global__ __launch_bounds__(256) void compact_k(const int* __restrict__ eidx,
                                                 int* __restrict__ rowsrc, int* __restrict__ ofs) {
  __shared__ unsigned long long sc[256];
  __shared__ int soff[5];
  const int tid = threadIdx.x;
  int myE[8];
  unsigned long long c = 0;
#pragma unroll
  for (int i = 0; i < 8; ++i) {
    int e = eidx[tid * 8 + i];
    myE[i] = e;
    c += 1ull << (e * 16);
  }
  sc[tid] = c;
  __syncthreads();
  for (int o = 1; o < 256; o <<= 1) {
    unsigned long long v = (tid >= o) ? sc[tid - o] : 0ull;
    __syncthreads();
    sc[tid] += v;
    __syncthreads();
  }
  unsigned long long incl = sc[tid], tot = sc[255];
  unsigned long long excl = incl - c;
  if (tid == 0) {
    int off = 0;
    for (int e = 0; e < 4; ++e) {
      soff[e] = off;
      int cnt = (int)((tot >> (e * 16)) & 0xffff);
      off += (cnt + 127) & ~127;
    }
    soff[4] = off;
    for (int e = 0; e < 5; ++e) ofs[e] = soff[e];
  }
  __syncthreads();
  for (int r = tid; r < 2560; r += 256) rowsrc[r] = -1;
  __threadfence_block();
  __syncthreads();
  int rank[4];
#pragma unroll
  for (int e = 0; e < 4; ++e) rank[e] = (int)((excl >> (e * 16)) & 0xffff);
#pragma unroll
  for (int i = 0; i < 8; ++i) {
    int e = myE[i];
    rowsrc[soff[e] + rank[e]] = tid * 8 + i;
    rank[e]++;
  }
}

// ---------------- gather x rows (f32 -> bf16, rho-permuted cols) ----------------
__global__ __launch_bounds__(256) void gather_k(const float* __restrict__ x, const int* __restrict__ rowsrc,
                                                const int* __restrict__ ofs, u16* __restrict__ xg) {
  int r = blockIdx.x;
  if (r >= ofs[4]) return;
  int s = rowsrc[r];
  int c = threadIdx.x;
  float4 v = (s >= 0) ? ((const float4*)(x + (int64_t)s * 1024))[c] : float4{0.f, 0.f, 0.f, 0.f};
  ushort4 o;
  o.x = f2bf(v.x); o.y = f2bf(v.y); o.z = f2bf(v.z); o.w = f2bf(v.w);
  int t = c & 7, blk = c >> 3;
  int si = blk * 8 + ((t & 3) << 1) + (t >> 2);
  ((ushort4*)(xg + (int64_t)r * 1024))[si] = o;
}

// ---------------- host ----------------
extern "C" void kernel_launch(void* const* d_in, const int* in_sizes, int n_in,
                              void* d_out, int out_size, void* d_ws, size_t ws_size,
                              hipStream_t stream) {
  const float* src = (const float*)d_in[0];
  const float* Wq  = (const float*)d_in[1];
  const float* bq  = (const float*)d_in[2];
  const float* Wk  = (const float*)d_in[3];
  const float* bk  = (const float*)d_in[4];
  const float* Wv  = (const float*)d_in[5];
  const float* bv  = (const float*)d_in[6];
  const float* Wo  = (const float*)d_in[7];
  const float* bo  = (const float*)d_in[8];
  const float* rw  = (const float*)d_in[9];
  const float* rb  = (const float*)d_in[10];
  const float* W1  = (const float*)d_in[11];
  const float* b1  = (const float*)d_in[12];
  const float* W2  = (const float*)d_in[13];
  const float* b2  = (const float*)d_in[14];
  const float* g1  = (const float*)d_in[15];
  const float* be1 = (const float*)d_in[16];
  const float* g2  = (const float*)d_in[17];
  const float* be2 = (const float*)d_in[18];
  float* out = (float*)d_out;

  char* base = (char*)d_ws;
  size_t off = 0;
  auto alloc = [&](size_t bytes) -> char* {
    char* p = base + off;
    off += (bytes + 255) & ~(size_t)255;
    return p;
  };
  const size_t MB = 1ull << 20;
  u16* srcH = (u16*)alloc(4 * MB);
  u16* srcL = (u16*)alloc(4 * MB);
  u16* WqkvTh = (u16*)alloc(6 * MB);
  u16* WqkvTl = (u16*)alloc(6 * MB);
  u16* WoTh = (u16*)alloc(2 * MB);
  u16* WoTl = (u16*)alloc(2 * MB);
  float* bqkv = (float*)alloc(16 * 1024);
  u16* qkvH = (u16*)alloc(12 * MB);
  u16* qkvL = (u16*)alloc(12 * MB);
  u16* hbuf = (u16*)qkvH;  // alias: 20MB over qkvH+qkvL (24MB), dead by FFN time
  u16* vTH = (u16*)alloc(4 * MB); u16* vTL = (u16*)alloc(4 * MB);
  float* scores = (float*)alloc(64 * MB);  // probs hi/lo; later W1T/W2T
  u16* W1T = (u16*)scores;
  u16* W2T = (u16*)scores + 16ull * 1024 * 1024;
  u16* attnH = (u16*)alloc(4 * MB); u16* attnL = (u16*)alloc(4 * MB);
  u16* xg = (u16*)attnH;  // alias: dead after Wo GEMM
  float* woOut = (float*)alloc(8 * MB);
  float* xbuf = (float*)alloc(8 * MB);
  float* partials = (float*)alloc(40 * MB);  // 4 x 2560 x 1024 f32
  int* eidx   = (int*)alloc(2048 * 4);
  int* rowsrc = (int*)alloc(2560 * 4);
  int* ofs    = (int*)alloc(32);
  (void)ws_size; (void)in_sizes; (void)n_in; (void)out_size;

  dim3 tb(32, 8);

  // Phase 0 (1 launch): src split + 4 attention weight transposes + bias concat
  prep1_k<<<3084, 256, 0, stream>>>(src, Wq, Wk, Wv, Wo, bq, bk, bv,
                                    srcH, srcL, WqkvTh, WqkvTl, WoTh, WoTl, bqkv);

  // Phase 1: fused QKV projection (bf16x3) -> qkv hi/lo [2048][3072], cols rho'd
  {
    GemmArgs g{};
    g.Ah = srcH; g.Al = srcL; g.lda = 1024;
    g.Bh = WqkvTh; g.Bl = WqkvTl; g.ldb = 1024;
    g.Ch = qkvH; g.Cl = qkvL; g.ldc = 3072;
    g.bias = bqkv; g.K = 1024; g.Z2 = 0;
    g.NX = 16; g.NY = 32; g.YG = 8;
    gemm_k<128, 96, true, 1, true, 2, true><<<dim3(512), 256, 0, stream>>>(g);
  }
  // v slice -> vT [b][d][t] hi/lo (lossless re-layout, t rho'd)
  transpose_pair_k<<<dim3(32, 16, 4), tb, 0, stream>>>(qkvH, qkvL, vTH, vTL);

  // Phase 2: FUSED scores (bf16x3, bitwise-identical) + softmax -> probs hi/lo
  attn_sm_k<<<dim3(4, 64), 512, 0, stream>>>(qkvH, qkvL, (u16*)scores);

  // PV: attn = probs @ v (bf16x3) -> attn hi/lo, d-cols rho'd
  {
    GemmArgs g{};
    g.Ah = (const u16*)scores; g.Al = (const u16*)scores + 512; g.lda = 1024;
    g.Bh = vTH; g.Bl = vTL; g.ldb = 512;
    g.Ch = attnH; g.Cl = attnL; g.ldc = 1024;
    g.K = 512; g.Z2 = 16;
    g.aZ1 = 16ll * 512 * 1024; g.aZ2 = 512ll * 1024;
    g.bZ1 = 1024ll * 512;      g.bZ2 = 64ll * 512;
    g.cZ1 = 512ll * 1024;      g.cZ2 = 64;
    gemm_k<64, 64, true, 1, true, 3, false><<<dim3(8, 1, 64), 256, 0, stream>>>(g);
  }
  // Wo projection (bf16x3) + bias -> plain f32 (feeds LN/residual)
  {
    GemmArgs g{};
    g.Ah = attnH; g.Al = attnL; g.lda = 1024;
    g.Bh = WoTh; g.Bl = WoTl; g.ldb = 1024;
    g.C = woOut; g.ldc = 1024;
    g.bias = bo; g.K = 1024; g.Z2 = 0;
    gemm_k<64, 64, true, 0, false, 3, false><<<dim3(32, 16, 1), 256, 0, stream>>>(g);
  }
  // ln1 + fused router
  ln_router_k<<<2048, 256, 0, stream>>>(src, woOut, g1, be1, rw, rb, xbuf, eidx);

  // Phase 3: routing
  compact_k<<<1, 256, 0, stream>>>(eidx, rowsrc, ofs);
  gather_k<<<2560, 256, 0, stream>>>(xbuf, rowsrc, ofs, xg);

  // FFN weights -> bf16 transposed (1 launch, into dead scores region), k-dims rho'd
  prep2_k<<<8192, 256, 0, stream>>>(W1, W2, W1T, W2T);

  // FFN1: h = relu(xg @ W1[e] + b1[e]) -> bf16, cols rho'd
  {
    GemmArgs g{};
    g.Ah = xg; g.lda = 1024;
    g.Bh = W1T; g.ldb = 1024;
    g.Ch = hbuf; g.ldc = 4096;
    g.bias = b1; g.biasStrE = 4096;
    g.K = 1024; g.Z2 = 0;
    g.ofs = ofs; g.bStrE = 4096ll * 1024;
    g.NX = 20; g.NY = 32; g.YG = 16;
    gemm_k<128, 128, false, 2, true, 3, true><<<dim3(640), 256, 0, stream>>>(g);
  }
  // FFN2 split-K x4, 128x128 tile: partial[c] = h[:, c*1024:...] @ W2[e][c*1024:..., :]
  {
    GemmArgs g{};
    g.Ah = hbuf; g.lda = 4096;
    g.Bh = W2T; g.ldb = 4096;
    g.C = partials; g.ldc = 1024;
    g.bias = nullptr;
    g.K = 1024; g.Z2 = 4;
    g.aZ1 = 0; g.aZ2 = 1024;
    g.bZ1 = 0; g.bZ2 = 1024;
    g.cZ1 = 0; g.cZ2 = 2560ll * 1024;
    g.ofs = ofs; g.bStrE = 4096ll * 1024;
    g.NX = 20; g.NY = 8; g.YG = 8;
    gemm_k<128, 128, false, 0, false, 3, true><<<dim3(640), 256, 0, stream>>>(g);
  }
  // fused: reduce split-K(4) + b2 + residual + LN2 + scatter to out
  reduce_ln_k<<<2560, 256, 0, stream>>>(partials, rowsrc, ofs, b2, xbuf, g2, be2, out);
}